// Round 6
// baseline (275.466 us; speedup 1.0000x reference)
//
#include <hip/hip_runtime.h>
#include <stdint.h>

typedef unsigned short u16;
typedef unsigned int u32;
typedef __attribute__((ext_vector_type(8))) short s16x8;
typedef __attribute__((ext_vector_type(8))) __bf16 bf16x8;
typedef __attribute__((ext_vector_type(4))) float f32x4;
typedef __attribute__((ext_vector_type(4))) u32 u32x4;
typedef __attribute__((ext_vector_type(4))) u16 u16x4;

__device__ __forceinline__ u32 f2bf(float f){
  u32 u = __builtin_bit_cast(u32, f);
  return (u + 0x7FFFu + ((u >> 16) & 1u)) >> 16;
}

__device__ __forceinline__ f32x4 mfma16(s16x8 a, s16x8 b, f32x4 c){
  return __builtin_amdgcn_mfma_f32_16x16x32_bf16(
      __builtin_bit_cast(bf16x8, a), __builtin_bit_cast(bf16x8, b), c, 0, 0, 0);
}

__device__ __forceinline__ void gload16(const void* g, void* l){
  __builtin_amdgcn_global_load_lds(
      (const __attribute__((address_space(1))) void*)g,
      (__attribute__((address_space(3))) void*)l, 16, 0, 0);
}

__device__ __forceinline__ u32 cvtpk(float lo, float hi){
  u32 r;
  asm("v_cvt_pk_bf16_f32 %0, %1, %2" : "=v"(r) : "v"(lo), "v"(hi));
  return r;
}

__device__ __forceinline__ float dpp_reduce16(float x){
  float y;
  asm("v_add_f32_dpp %0, %1, %1 row_ror:8 row_mask:0xf bank_mask:0xf"
      : "=&v"(y) : "v"(x));
  asm("v_add_f32_dpp %0, %1, %1 row_ror:4 row_mask:0xf bank_mask:0xf"
      : "=&v"(x) : "v"(y));
  asm("v_add_f32_dpp %0, %1, %1 quad_perm:[2,3,0,1] row_mask:0xf bank_mask:0xf"
      : "=&v"(y) : "v"(x));
  asm("v_add_f32_dpp %0, %1, %1 quad_perm:[1,0,3,2] row_mask:0xf bank_mask:0xf"
      : "=&v"(x) : "v"(y));
  return x;
}

__device__ __forceinline__ void unpack8(s16x8 v, float* f){
  u32x4 u = __builtin_bit_cast(u32x4, v);
  #pragma unroll
  for (int i = 0; i < 4; ++i){
    f[2*i]   = __builtin_bit_cast(float, u[i] << 16);
    f[2*i+1] = __builtin_bit_cast(float, u[i] & 0xffff0000u);
  }
}

// ---------- kprep: X bf16, XTF (transposed frag layout), WF frags, w1/mb ----------
// XTF[b][ct 8][lcg 1024][g 4][l15 16][e 8] = x[row=lcg*32+g*8+e][col=ct*16+l15]
__global__ __launch_bounds__(256) void kprep(
    const float* __restrict__ v, const float* __restrict__ Wk, const float* __restrict__ Wv,
    const float* __restrict__ Wkb, const float* __restrict__ Wvb,
    u16* __restrict__ X, u16* __restrict__ XTF, u16* __restrict__ WF,
    float* __restrict__ w1u, float* __restrict__ scn)
{
  const int tid = threadIdx.x;
  if (blockIdx.x < 512){
    __shared__ u16 sx[128 * 132];
    const int blk = blockIdx.x, b = blk >> 8, lch = blk & 255;
    const float* vb = v + ((size_t)b * 32768 + lch * 128) * 128;
    u16* xb = X + ((size_t)b * 32768 + lch * 128) * 128;
    #pragma unroll
    for (int i = 0; i < 16; ++i){
      int flat = i * 1024 + tid * 4;
      int r = flat >> 7, c = flat & 127;
      float4 f = *(const float4*)(vb + flat);
      u16x4 o; o.x = (u16)f2bf(f.x); o.y = (u16)f2bf(f.y); o.z = (u16)f2bf(f.z); o.w = (u16)f2bf(f.w);
      *(u16x4*)(xb + flat) = o;
      *(u16x4*)(&sx[r * 132 + c]) = o;
    }
    __syncthreads();
    #pragma unroll
    for (int it = 0; it < 8; ++it){
      int t = it * 256 + tid;
      int l15 = t & 15, gg = (t >> 4) & 3, lc = (t >> 6) & 3, ct = t >> 8;
      u16 tmp[8];
      #pragma unroll
      for (int e = 0; e < 8; ++e)
        tmp[e] = sx[(lc * 32 + gg * 8 + e) * 132 + ct * 16 + l15];
      u32 w0 = (u32)tmp[0] | ((u32)tmp[1] << 16);
      u32 w1_ = (u32)tmp[2] | ((u32)tmp[3] << 16);
      u32 w2 = (u32)tmp[4] | ((u32)tmp[5] << 16);
      u32 w3 = (u32)tmp[6] | ((u32)tmp[7] << 16);
      u32x4 uu = {w0, w1_, w2, w3};
      size_t off = ((((size_t)b * 8 + ct) * 1024 + (lch * 4 + lc)) * 4 + gg) * 128 + (size_t)l15 * 8;
      *reinterpret_cast<u32x4*>(XTF + off) = uu;
    }
  } else {
    const int hp = blockIdx.x - 512, h = hp & 7, proj = hp >> 3;
    const float* W = proj ? Wv : Wk;
    const float* pb = (proj ? Wvb : Wkb) + h * 128;
    for (int i = tid; i < 16384; i += 256){
      int e = i & 7, ln = (i >> 3) & 63, ks = (i >> 9) & 3, nt = i >> 11;
      int c = ks * 32 + (ln >> 4) * 8 + e;
      int n = nt * 16 + (ln & 15);
      WF[proj * 131072 + h * 16384 + i] = (u16)f2bf(W[(size_t)c * 1024 + h * 128 + n]);
    }
    if (tid < 128){
      float s = 0.f;
      const float* p = W + (size_t)tid * 1024 + h * 128;
      for (int n = 0; n < 128; ++n) s += p[n];
      w1u[hp * 128 + tid] = s * 0.0078125f;
    }
    if (tid == 0){
      float mb = 0.f;
      for (int n = 0; n < 128; ++n) mb += pb[n];
      scn[hp] = mb * 0.0078125f;
    }
  }
}

// ---------- kstat: proj both heads' K,V, per-row LN stats only -> c,a,b ----------
__global__ __launch_bounds__(512, 2) void kstat(
    const u16* __restrict__ X, const u16* __restrict__ WF,
    const float* __restrict__ bk, const float* __restrict__ bv,
    float* __restrict__ cF, u16* __restrict__ cab)
{
  extern __shared__ char sW[];   // 64 KiB: WkF | WvF frags
  const int tid = threadIdx.x, wid = tid >> 6, lane = tid & 63, g = lane >> 4, l15 = lane & 15;
  const int bh = blockIdx.x >> 4, grp = blockIdx.x & 15;
  const int b = bh >> 3, h = bh & 7;
  {
    const char* wk = (const char*)(WF + h * 16384);
    const char* wv = (const char*)(WF + 131072 + h * 16384);
    #pragma unroll
    for (int i = 0; i < 4; ++i){
      u32 o = i * 8192 + tid * 16;
      gload16(wk + o, sW + o);
      gload16(wv + o, sW + 32768 + o);
    }
  }
  float br[2][8];
  #pragma unroll
  for (int nt = 0; nt < 8; ++nt){
    br[0][nt] = bk[h * 128 + nt * 16 + l15];
    br[1][nt] = bv[h * 128 + nt * 16 + l15];
  }
  asm volatile("s_waitcnt vmcnt(0)" ::: "memory");
  __builtin_amdgcn_s_barrier();

  const u16* Xb = X + (size_t)b * 32768 * 128;
  float* cFb = cF + (size_t)bh * 32768;
  u16* cabb = cab + (size_t)bh * 3 * 32768;

  #pragma unroll 1
  for (int it = 0; it < 4; ++it){
    const int rb = grp * 2048 + it * 512 + wid * 64;
    s16x8 af[4][4];
    #pragma unroll
    for (int mt = 0; mt < 4; ++mt)
      #pragma unroll
      for (int ks = 0; ks < 4; ++ks)
        af[mt][ks] = *(const s16x8*)(Xb + (size_t)(rb + mt * 16 + l15) * 128 + ks * 32 + g * 8);
    float rst[2][4][4];
    #pragma unroll
    for (int pj = 0; pj < 2; ++pj){
      f32x4 acc[4][8];
      #pragma unroll
      for (int mt = 0; mt < 4; ++mt)
        #pragma unroll
        for (int nt = 0; nt < 8; ++nt) acc[mt][nt] = f32x4{0.f, 0.f, 0.f, 0.f};
      #pragma unroll
      for (int ks = 0; ks < 4; ++ks)
        #pragma unroll
        for (int nt = 0; nt < 8; ++nt){
          s16x8 wf = *(const s16x8*)(sW + pj * 32768 + (nt * 4 + ks) * 1024 + lane * 16);
          #pragma unroll
          for (int mt = 0; mt < 4; ++mt)
            acc[mt][nt] = mfma16(af[mt][ks], wf, acc[mt][nt]);
        }
      #pragma unroll
      for (int mt = 0; mt < 4; ++mt){
        f32x4 s4 = {0.f,0.f,0.f,0.f}, q4 = {0.f,0.f,0.f,0.f};
        #pragma unroll
        for (int nt = 0; nt < 8; ++nt){
          f32x4 t = acc[mt][nt] + br[pj][nt];
          s4 += t; q4 += t * t;
        }
        #pragma unroll
        for (int j = 0; j < 4; ++j){
          float ss = dpp_reduce16(s4[j]);
          float qq = dpp_reduce16(q4[j]);
          float mu = ss * 0.0078125f;
          float var = qq * 0.0078125f - mu * mu;
          rst[pj][mt][j] = rsqrtf(var + 1e-5f);
        }
      }
    }
    #pragma unroll
    for (int mt = 0; mt < 4; ++mt)
      #pragma unroll
      for (int j = 0; j < 4; ++j){
        if (l15 == g * 4 + j){
          int row = rb + mt * 16 + l15;
          float a = rst[0][mt][j], bb = rst[1][mt][j], c = a * bb;
          cFb[row] = c;
          cabb[row] = (u16)f2bf(c);
          cabb[32768 + row] = (u16)f2bf(a);
          cabb[65536 + row] = (u16)f2bf(bb);
        }
      }
  }
}

// ---------- kS2: Spart[bh][grp] += [cX;c;a;b]^T [X|1]  (no barriers) ----------
__global__ __launch_bounds__(512, 4) void kS2(
    const u16* __restrict__ XTF, const float* __restrict__ cF, const u16* __restrict__ cab,
    float* __restrict__ Spart)
{
  const int tid = threadIdx.x, wid = tid >> 6, lane = tid & 63, g = lane >> 4, l15 = lane & 15;
  const int bh = blockIdx.x >> 4, grp = blockIdx.x & 15;
  const int b = bh >> 3;
  const int mtp = wid & 3, nth = wid >> 2;
  const u16* xtb = XTF + (size_t)b * 4194304;
  const float* cFb = cF + (size_t)bh * 32768;
  const u16* cab3 = cab + (size_t)bh * 3 * 32768 + (size_t)(l15 < 3 ? l15 : 0) * 32768;

  f32x4 accC[2][4], accB[2], accS = {0.f,0.f,0.f,0.f}, accS8 = {0.f,0.f,0.f,0.f};
  #pragma unroll
  for (int m2 = 0; m2 < 2; ++m2){
    accB[m2] = f32x4{0.f,0.f,0.f,0.f};
    #pragma unroll
    for (int q = 0; q < 4; ++q) accC[m2][q] = f32x4{0.f,0.f,0.f,0.f};
  }
  s16x8 bone;
  { u32 o = (l15 == 0) ? 0x3F803F80u : 0u; u32x4 t = {o, o, o, o};
    bone = __builtin_bit_cast(s16x8, t); }

  #pragma unroll 1
  for (int kst = 0; kst < 64; ++kst){
    const int lcg = grp * 64 + kst;
    const int l0 = lcg * 32;
    const size_t base = (size_t)(lcg * 4 + g) * 128 + (size_t)l15 * 8;
    float cs[8];
    { const float* cp = cFb + l0 + g * 8;
      float4 c0 = *(const float4*)cp, c1 = *(const float4*)(cp + 4);
      cs[0]=c0.x; cs[1]=c0.y; cs[2]=c0.z; cs[3]=c0.w;
      cs[4]=c1.x; cs[5]=c1.y; cs[6]=c1.z; cs[7]=c1.w; }
    s16x8 aS[2];
    #pragma unroll
    for (int m2 = 0; m2 < 2; ++m2){
      s16x8 a0 = *(const s16x8*)(xtb + (size_t)(2 * mtp + m2) * 524288 + base);
      float fa[8]; unpack8(a0, fa);
      u32x4 pv = { cvtpk(fa[0]*cs[0], fa[1]*cs[1]), cvtpk(fa[2]*cs[2], fa[3]*cs[3]),
                   cvtpk(fa[4]*cs[4], fa[5]*cs[5]), cvtpk(fa[6]*cs[6], fa[7]*cs[7]) };
      aS[m2] = __builtin_bit_cast(s16x8, pv);
    }
    s16x8 astr = *(const s16x8*)(cab3 + l0 + g * 8);
    if (l15 >= 3){ u32x4 z = {0,0,0,0}; astr = __builtin_bit_cast(s16x8, z); }
    #pragma unroll
    for (int q = 0; q < 4; ++q){
      s16x8 bf = *(const s16x8*)(xtb + (size_t)(4 * nth + q) * 524288 + base);
      accC[0][q] = mfma16(aS[0], bf, accC[0][q]);
      accC[1][q] = mfma16(aS[1], bf, accC[1][q]);
      if (q == mtp) accS = mfma16(astr, bf, accS);
    }
    if (nth == 0){
      accB[0] = mfma16(aS[0], bone, accB[0]);
      accB[1] = mfma16(aS[1], bone, accB[1]);
      if (wid == 0) accS8 = mfma16(astr, bone, accS8);
    }
  }
  float* Sp = Spart + ((size_t)bh * 16 + grp) * 19008;   // 132*144
  #pragma unroll
  for (int m2 = 0; m2 < 2; ++m2)
    #pragma unroll
    for (int q = 0; q < 4; ++q)
      #pragma unroll
      for (int j = 0; j < 4; ++j)
        Sp[((2*mtp + m2)*16 + g*4 + j) * 144 + (4*nth + q)*16 + l15] = accC[m2][q][j];
  if (g == 0){
    #pragma unroll
    for (int j = 0; j < 3; ++j)
      Sp[(128 + j) * 144 + wid * 16 + l15] = accS[j];
  }
  if (nth == 0 && l15 == 0){
    #pragma unroll
    for (int m2 = 0; m2 < 2; ++m2)
      #pragma unroll
      for (int j = 0; j < 4; ++j)
        Sp[((2*mtp + m2)*16 + g*4 + j) * 144 + 128] = accB[m2][j];
  }
  if (wid == 0 && g == 0 && l15 == 0){
    #pragma unroll
    for (int j = 0; j < 3; ++j)
      Sp[(128 + j) * 144 + 128] = accS8[j];
  }
}

// ---------- kred: S = sum over grp of Spart ----------
__global__ __launch_bounds__(256) void kred(const float* __restrict__ Spart, float* __restrict__ S){
  int bh = blockIdx.x, r = blockIdx.y, c = threadIdx.x;
  if (c >= 144) return;
  float s = 0.f;
  const float* p = Spart + (size_t)bh * 16 * 19008 + r * 144 + c;
  #pragma unroll
  for (int gq = 0; gq < 16; ++gq) s += p[(size_t)gq * 19008];
  S[(size_t)bh * 19008 + r * 144 + c] = s;
}

// ---------- kfoldA: G = W~k^T S2 W~v + rank1 + LN gamma/beta corrections -> AM ----------
__global__ __launch_bounds__(256) void kfoldA(
    const float* __restrict__ S, const float* __restrict__ Wk, const float* __restrict__ Wv,
    const float* __restrict__ Wkb, const float* __restrict__ Wvb,
    const float* __restrict__ w1u, const float* __restrict__ scn,
    const float* __restrict__ gk, const float* __restrict__ bbk,
    const float* __restrict__ gv, const float* __restrict__ bbv,
    float* __restrict__ AM)
{
  extern __shared__ float fsm[];
  float* sA = fsm;                 // [128][129]
  float* sS = fsm + 16512;         // [128][33]
  float* svt = fsm + 20736;        // [32]
  float* svb = fsm + 20768;        // [32]
  float* skt = fsm + 20800;        // [128]
  float* skb = fsm + 20928;        // [128]
  const int blk = blockIdx.x, bh = blk >> 2, es = blk & 3;
  const int h = bh & 7;
  const int tid = threadIdx.x;
  const float* Sg = S + (size_t)bh * 19008;
  const float mbk = scn[h], mbv = scn[8 + h];

  for (int idx = tid; idx < 16384; idx += 256){
    int r = idx >> 7, c = idx & 127;
    sA[r * 129 + c] = Sg[r * 144 + c];
  }
  for (int idx = tid; idx < 4096; idx += 256){
    int c = idx >> 5, j = idx & 31;
    sS[c * 33 + j] = Wv[(size_t)c * 1024 + h * 128 + es * 32 + j] - w1u[(8 + h) * 128 + c];
  }
  __syncthreads();
  if (tid < 32){
    float t = 0.f, tb = 0.f;
    for (int c = 0; c < 128; ++c){
      float wv = sS[c * 33 + tid];
      t  += Sg[128 * 144 + c] * wv;
      tb += Sg[130 * 144 + c] * wv;
    }
    svt[tid] = t;
    svb[tid] = tb + Sg[130 * 144 + 128] * (Wvb[h * 128 + es * 32 + tid] - mbv);
  }
  const int r0 = (tid >> 4) * 8, e0 = (tid & 15) * 2;
  float t8[8][2] = {};
  for (int c = 0; c < 128; ++c){
    float w0 = sS[c * 33 + e0], w1_ = sS[c * 33 + e0 + 1];
    #pragma unroll
    for (int i = 0; i < 8; ++i){
      float a = sA[(r0 + i) * 129 + c];
      t8[i][0] += a * w0; t8[i][1] += a * w1_;
    }
  }
  __syncthreads();
  #pragma unroll
  for (int i = 0; i < 8; ++i){
    sS[(r0 + i) * 33 + e0] = t8[i][0];
    sS[(r0 + i) * 33 + e0 + 1] = t8[i][1];
  }
  for (int idx = tid; idx < 16384; idx += 256){
    int c = idx >> 7, n = idx & 127;
    sA[c * 129 + n] = Wk[(size_t)c * 1024 + h * 128 + n] - w1u[h * 128 + c];
  }
  __syncthreads();
  if (tid < 128){
    float t = 0.f, ta = 0.f;
    for (int c = 0; c < 128; ++c){
      float wk = sA[c * 129 + tid];
      t  += Sg[128 * 144 + c] * wk;
      ta += Sg[129 * 144 + c] * wk;
    }
    skt[tid] = t;
    skb[tid] = ta + Sg[129 * 144 + 128] * (Wkb[h * 128 + tid] - mbk);
  }
  float g8[8][2] = {};
  for (int c = 0; c < 128; ++c){
    float t0 = sS[c * 33 + e0], t1 = sS[c * 33 + e0 + 1];
    #pragma unroll
    for (int i = 0; i < 8; ++i){
      float wk = sA[c * 129 + (r0 + i)];
      g8[i][0] += wk * t0; g8[i][1] += wk * t1;
    }
  }
  __syncthreads();
  const float s0 = Sg[128 * 144 + 128];
  #pragma unroll
  for (int i = 0; i < 8; ++i){
    int n = r0 + i;
    float btk = Wkb[h * 128 + n] - mbk;
    #pragma unroll
    for (int jj = 0; jj < 2; ++jj){
      int j = e0 + jj, dv = es * 32 + j;
      float btv = Wvb[h * 128 + dv] - mbv;
      float G = g8[i][jj] + skt[n] * btv + btk * svt[j] + s0 * btk * btv;
      float am = gk[h*128+n] * (gv[h*128+dv] * G + skb[n] * bbv[h*128+dv])
               + bbk[h*128+n] * (gv[h*128+dv] * svb[j] + 32768.f * bbv[h*128+dv]);
      AM[(size_t)bh * 16384 + n * 128 + dv] = am;
    }
  }
}

// ---------- kfoldB: T1 = AM@Wo ; W4F += frag(Wq@T1)/n ; c4 ----------
__global__ __launch_bounds__(256) void kfoldB(
    const float* __restrict__ AM, const float* __restrict__ Wo,
    const float* __restrict__ Wq, const float* __restrict__ Wq_b,
    const float* __restrict__ Wo_b, float* __restrict__ W4F, float* __restrict__ c4)
{
  extern __shared__ float fsm[];
  float* sA = fsm;
  float* sS = fsm + 128 * 129;
  int blk = blockIdx.x;
  int bh = blk >> 2, eq = blk & 3;
  int b = bh >> 3, hs = bh & 7;
  int tid = threadIdx.x;

  for (int idx = tid; idx < 16384; idx += 256){
    int r = idx >> 7, c = idx & 127;
    sA[r * 129 + c] = AM[(size_t)bh * 16384 + idx];
  }
  for (int idx = tid; idx < 4096; idx += 256){
    int r = idx >> 5, c = idx & 31;
    sS[r * 33 + c] = Wo[(size_t)hs * 16384 + r * 128 + eq * 32 + c];
  }
  __syncthreads();

  int r0 = (tid >> 4) * 8, e0 = (tid & 15) * 2;
  float t8[8][2] = {};
  for (int c = 0; c < 128; ++c){
    float wv0 = sS[c * 33 + e0], wv1 = sS[c * 33 + e0 + 1];
    #pragma unroll
    for (int i = 0; i < 8; ++i){
      float a = sA[(r0 + i) * 129 + c];
      t8[i][0] += a * wv0; t8[i][1] += a * wv1;
    }
  }
  __syncthreads();
  #pragma unroll
  for (int i = 0; i < 8; ++i){
    sS[(r0 + i) * 33 + e0]     = t8[i][0];
    sS[(r0 + i) * 33 + e0 + 1] = t8[i][1];
  }
  for (int idx = tid; idx < 16384; idx += 256){
    int r = idx >> 7, c = idx & 127;
    sA[r * 129 + c] = Wq[(size_t)r * 1024 + hs * 128 + c];
  }
  __syncthreads();

  float a8[8][2] = {};
  for (int d = 0; d < 128; ++d){
    float t0 = sS[d * 33 + e0], t1 = sS[d * 33 + e0 + 1];
    #pragma unroll
    for (int i = 0; i < 8; ++i){
      float w = sA[(r0 + i) * 129 + d];
      a8[i][0] += w * t0; a8[i][1] += w * t1;
    }
  }
  const float inv_n = 0.0009765625f;
  #pragma unroll
  for (int i = 0; i < 8; ++i)
    #pragma unroll
    for (int j = 0; j < 2; ++j){
      int cc = r0 + i, nn = eq * 32 + e0 + j;
      int o = ((nn >> 4) * 4 + (cc >> 5)) * 512 + ((cc >> 3) & 3) * 128
            + (nn & 15) * 8 + (cc & 7);
      atomicAdd(W4F + (size_t)b * 16384 + o, a8[i][j] * inv_n);
    }
  if (tid < 32){
    float s = 0.f;
    for (int d = 0; d < 128; ++d) s += Wq_b[hs * 128 + d] * sS[d * 33 + tid];
    if (hs == 0) s += Wo_b[eq * 32 + tid];
    atomicAdd(c4 + b * 128 + eq * 32 + tid, s * inv_n);
  }
}

// ---------- kout = x @ W4[b] + c4[b] ----------
__global__ __launch_bounds__(256, 4) void kout(
    const u16* __restrict__ X, const float* __restrict__ W4F,
    const float* __restrict__ c4, float* __restrict__ out)
{
  __shared__ char sW[32768];
  const int tid = threadIdx.x, wid = tid >> 6, lane = tid & 63, g = lane >> 4, l15 = lane & 15;
  const int blk = blockIdx.x, b = blk >> 8, ch = blk & 255;
  {
    const float* w4b = W4F + (size_t)b * 16384;
    #pragma unroll
    for (int it2 = 0; it2 < 16; ++it2){
      int idx = it2 * 1024 + tid * 4;
      float4 f = *(const float4*)(w4b + idx);
      uint2 w; w.x = cvtpk(f.x, f.y); w.y = cvtpk(f.z, f.w);
      *(uint2*)(sW + idx * 2) = w;
    }
  }
  const char* xr = (const char*)(X + ((size_t)b * 32768 + ch * 128 + wid * 32 + l15) * 128) + g * 16;
  s16x8 af[2][4];
  #pragma unroll
  for (int mt = 0; mt < 2; ++mt)
    #pragma unroll
    for (int ks = 0; ks < 4; ++ks)
      af[mt][ks] = *(const s16x8*)(xr + mt * 4096 + ks * 64);
  __syncthreads();

  f32x4 acc[2][8];
  #pragma unroll
  for (int mt = 0; mt < 2; ++mt)
    #pragma unroll
    for (int nt = 0; nt < 8; ++nt) acc[mt][nt] = f32x4{0.f, 0.f, 0.f, 0.f};

  const u32 wread = (u32)(lane * 16);
  #pragma unroll
  for (int ks = 0; ks < 4; ++ks)
    #pragma unroll
    for (int nt = 0; nt < 8; ++nt){
      s16x8 wf = *(const s16x8*)(sW + wread + (nt * 4 + ks) * 1024);
      acc[0][nt] = mfma16(af[0][ks], wf, acc[0][nt]);
      acc[1][nt] = mfma16(af[1][ks], wf, acc[1][nt]);
    }
  float* ob = out + ((size_t)b * 32768 + ch * 128 + wid * 32) * 128;
  #pragma unroll
  for (int nt = 0; nt < 8; ++nt){
    float c4v = c4[b * 128 + nt * 16 + l15];
    #pragma unroll
    for (int mt = 0; mt < 2; ++mt)
      #pragma unroll
      for (int j = 0; j < 4; ++j)
        ob[(mt * 16 + g * 4 + j) * 128 + nt * 16 + l15] = acc[mt][nt][j] + c4v;
  }
}

extern "C" void kernel_launch(void* const* d_in, const int* in_sizes, int n_in,
                              void* d_out, int out_size, void* d_ws, size_t ws_size,
                              hipStream_t stream){
  const float* v    = (const float*)d_in[0];
  const float* Wq_w = (const float*)d_in[1];
  const float* Wq_b = (const float*)d_in[2];
  const float* Wk_w = (const float*)d_in[3];
  const float* Wk_b = (const float*)d_in[4];
  const float* Wv_w = (const float*)d_in[5];
  const float* Wv_b = (const float*)d_in[6];
  const float* Wo_w = (const float*)d_in[7];
  const float* Wo_b = (const float*)d_in[8];
  const float* lnk_g = (const float*)d_in[9];
  const float* lnk_b = (const float*)d_in[10];
  const float* lnv_g = (const float*)d_in[11];
  const float* lnv_b = (const float*)d_in[12];

  char* ws = (char*)d_ws;
  u16*   X     = (u16*)  (ws);                 // 16,777,216
  u16*   XTF   = (u16*)  (ws + 16777216);      // 16,777,216
  u16*   WF    = (u16*)  (ws + 33554432);      // 524,288
  float* cF    = (float*)(ws + 34078720);      // 2,097,152
  u16*   cab   = (u16*)  (ws + 36175872);      // 3,145,728
  float* w1u   = (float*)(ws + 39321600);      // 8,192
  float* scn   = (float*)(ws + 39329792);      // 128
  float* Spart = (float*)(ws + 39329920);      // 19,464,192
  float* S     = (float*)(ws + 58794112);      // 1,216,512
  float* AM    = (float*)(ws + 60010624);      // 1,048,576
  float* W4F   = (float*)(ws + 61059200);      // 131,072
  float* c4    = (float*)(ws + 61190272);      // 1,024

  hipMemsetAsync(ws + 61059200, 0, 132096, stream);   // W4F + c4

  hipLaunchKernelGGL(kprep, dim3(528), dim3(256), 0, stream,
                     v, Wk_w, Wv_w, Wk_b, Wv_b, X, XTF, WF, w1u, scn);

  (void)hipFuncSetAttribute((const void*)kstat,
                            hipFuncAttributeMaxDynamicSharedMemorySize, 65536);
  hipLaunchKernelGGL(kstat, dim3(256), dim3(512), 65536, stream,
                     X, WF, Wk_b, Wv_b, cF, cab);

  hipLaunchKernelGGL(kS2, dim3(256), dim3(512), 0, stream, XTF, cF, cab, Spart);

  hipLaunchKernelGGL(kred, dim3(16, 132), dim3(256), 0, stream, Spart, S);

  (void)hipFuncSetAttribute((const void*)kfoldA,
                            hipFuncAttributeMaxDynamicSharedMemorySize, 84224);
  hipLaunchKernelGGL(kfoldA, dim3(64), dim3(256), 84224, stream,
                     S, Wk_w, Wv_w, Wk_b, Wv_b, w1u, scn,
                     lnk_g, lnk_b, lnv_g, lnv_b, AM);

  (void)hipFuncSetAttribute((const void*)kfoldB,
                            hipFuncAttributeMaxDynamicSharedMemorySize, 82944);
  hipLaunchKernelGGL(kfoldB, dim3(64), dim3(256), 82944, stream,
                     AM, Wo_w, Wq_w, Wq_b, Wo_b, W4F, c4);

  hipLaunchKernelGGL(kout, dim3(512), dim3(256), 0, stream, X, W4F, c4, (float*)d_out);
}

// Round 7
// 242.602 us; speedup vs baseline: 1.1355x; 1.1355x over previous
//
#include <hip/hip_runtime.h>
#include <stdint.h>

typedef unsigned short u16;
typedef unsigned int u32;
typedef __attribute__((ext_vector_type(8))) short s16x8;
typedef __attribute__((ext_vector_type(8))) __bf16 bf16x8;
typedef __attribute__((ext_vector_type(4))) float f32x4;
typedef __attribute__((ext_vector_type(4))) u32 u32x4;
typedef __attribute__((ext_vector_type(4))) u16 u16x4;

__device__ __forceinline__ u32 f2bf(float f){
  u32 u = __builtin_bit_cast(u32, f);
  return (u + 0x7FFFu + ((u >> 16) & 1u)) >> 16;
}

__device__ __forceinline__ f32x4 mfma16(s16x8 a, s16x8 b, f32x4 c){
  return __builtin_amdgcn_mfma_f32_16x16x32_bf16(
      __builtin_bit_cast(bf16x8, a), __builtin_bit_cast(bf16x8, b), c, 0, 0, 0);
}

__device__ __forceinline__ void gload16(const void* g, void* l){
  __builtin_amdgcn_global_load_lds(
      (const __attribute__((address_space(1))) void*)g,
      (__attribute__((address_space(3))) void*)l, 16, 0, 0);
}

__device__ __forceinline__ u32 cvtpk(float lo, float hi){
  u32 r;
  asm("v_cvt_pk_bf16_f32 %0, %1, %2" : "=v"(r) : "v"(lo), "v"(hi));
  return r;
}

__device__ __forceinline__ float dpp_reduce16(float x){
  float y;
  asm("v_add_f32_dpp %0, %1, %1 row_ror:8 row_mask:0xf bank_mask:0xf"
      : "=&v"(y) : "v"(x));
  asm("v_add_f32_dpp %0, %1, %1 row_ror:4 row_mask:0xf bank_mask:0xf"
      : "=&v"(x) : "v"(y));
  asm("v_add_f32_dpp %0, %1, %1 quad_perm:[2,3,0,1] row_mask:0xf bank_mask:0xf"
      : "=&v"(y) : "v"(x));
  asm("v_add_f32_dpp %0, %1, %1 quad_perm:[1,0,3,2] row_mask:0xf bank_mask:0xf"
      : "=&v"(x) : "v"(y));
  return x;
}

__device__ __forceinline__ void unpack8(s16x8 v, float* f){
  u32x4 u = __builtin_bit_cast(u32x4, v);
  #pragma unroll
  for (int i = 0; i < 4; ++i){
    f[2*i]   = __builtin_bit_cast(float, u[i] << 16);
    f[2*i+1] = __builtin_bit_cast(float, u[i] & 0xffff0000u);
  }
}

// ---------- kprep: X bf16, XTF (transposed frag layout), WF frags, w1/mb ----------
// XTF[b][ct 8][lcg 1024][g 4][l15 16][e 8] = x[row=lcg*32+g*8+e][col=ct*16+l15]
__global__ __launch_bounds__(256) void kprep(
    const float* __restrict__ v, const float* __restrict__ Wk, const float* __restrict__ Wv,
    const float* __restrict__ Wkb, const float* __restrict__ Wvb,
    u16* __restrict__ X, u16* __restrict__ XTF, u16* __restrict__ WF,
    float* __restrict__ w1u, float* __restrict__ scn)
{
  const int tid = threadIdx.x;
  if (blockIdx.x < 512){
    __shared__ u16 sx[128 * 132];
    const int blk = blockIdx.x, b = blk >> 8, lch = blk & 255;
    const float* vb = v + ((size_t)b * 32768 + lch * 128) * 128;
    u16* xb = X + ((size_t)b * 32768 + lch * 128) * 128;
    #pragma unroll
    for (int i = 0; i < 16; ++i){
      int flat = i * 1024 + tid * 4;
      int r = flat >> 7, c = flat & 127;
      float4 f = *(const float4*)(vb + flat);
      u16x4 o; o.x = (u16)f2bf(f.x); o.y = (u16)f2bf(f.y); o.z = (u16)f2bf(f.z); o.w = (u16)f2bf(f.w);
      *(u16x4*)(xb + flat) = o;
      *(u16x4*)(&sx[r * 132 + c]) = o;
    }
    __syncthreads();
    #pragma unroll
    for (int it = 0; it < 8; ++it){
      int t = it * 256 + tid;
      int l15 = t & 15, gg = (t >> 4) & 3, lc = (t >> 6) & 3, ct = t >> 8;
      u16 tmp[8];
      #pragma unroll
      for (int e = 0; e < 8; ++e)
        tmp[e] = sx[(lc * 32 + gg * 8 + e) * 132 + ct * 16 + l15];
      u32 w0 = (u32)tmp[0] | ((u32)tmp[1] << 16);
      u32 w1_ = (u32)tmp[2] | ((u32)tmp[3] << 16);
      u32 w2 = (u32)tmp[4] | ((u32)tmp[5] << 16);
      u32 w3 = (u32)tmp[6] | ((u32)tmp[7] << 16);
      u32x4 uu = {w0, w1_, w2, w3};
      size_t off = ((((size_t)b * 8 + ct) * 1024 + (lch * 4 + lc)) * 4 + gg) * 128 + (size_t)l15 * 8;
      *reinterpret_cast<u32x4*>(XTF + off) = uu;
    }
  } else {
    const int hp = blockIdx.x - 512, h = hp & 7, proj = hp >> 3;
    const float* W = proj ? Wv : Wk;
    const float* pb = (proj ? Wvb : Wkb) + h * 128;
    for (int i = tid; i < 16384; i += 256){
      int e = i & 7, ln = (i >> 3) & 63, ks = (i >> 9) & 3, nt = i >> 11;
      int c = ks * 32 + (ln >> 4) * 8 + e;
      int n = nt * 16 + (ln & 15);
      WF[proj * 131072 + h * 16384 + i] = (u16)f2bf(W[(size_t)c * 1024 + h * 128 + n]);
    }
    if (tid < 128){
      float s = 0.f;
      const float* p = W + (size_t)tid * 1024 + h * 128;
      for (int n = 0; n < 128; ++n) s += p[n];
      w1u[hp * 128 + tid] = s * 0.0078125f;
    }
    if (tid == 0){
      float mb = 0.f;
      for (int n = 0; n < 128; ++n) mb += pb[n];
      scn[hp] = mb * 0.0078125f;
    }
  }
}

// ---------- kstat v2: weights-in-registers proj -> per-row LN stats ----------
// 4 waves: {K,V} x {col-half}. Each wave: 16 weight frags in VGPRs, 64 rows/it.
__global__ __launch_bounds__(256, 2) void kstat(
    const u16* __restrict__ X, const u16* __restrict__ WF,
    const float* __restrict__ bk, const float* __restrict__ bv,
    float* __restrict__ aF, float* __restrict__ bF, float* __restrict__ cF)
{
  __shared__ float sstat[4][64][2];   // [proj*2+half][row][s,q]
  const int tid = threadIdx.x, wid = tid >> 6, lane = tid & 63, g = lane >> 4, l15 = lane & 15;
  const int bh = blockIdx.x >> 5, grp = blockIdx.x & 31;
  const int b = bh >> 3, h = bh & 7;
  const int proj = wid >> 1, half = wid & 1;

  s16x8 wf[4][4];
  {
    const u16* wbase = WF + proj * 131072 + h * 16384;
    #pragma unroll
    for (int nt = 0; nt < 4; ++nt)
      #pragma unroll
      for (int ks = 0; ks < 4; ++ks)
        wf[nt][ks] = *(const s16x8*)(wbase + (size_t)(((half * 4 + nt) * 4 + ks) * 512) + lane * 8);
  }
  const float* bias = proj ? bv : bk;
  float br[4];
  #pragma unroll
  for (int nt = 0; nt < 4; ++nt) br[nt] = bias[h * 128 + half * 64 + nt * 16 + l15];

  const u16* Xb = X + (size_t)b * 32768 * 128;
  const int rb0 = grp * 1024;
  float* aFb = aF + (size_t)bh * 32768;
  float* bFb = bF + (size_t)bh * 32768;
  float* cFb = cF + (size_t)bh * 32768;

  #pragma unroll 1
  for (int it = 0; it < 16; ++it){
    const int rb = rb0 + it * 64;
    s16x8 af[4][4];
    #pragma unroll
    for (int mt = 0; mt < 4; ++mt)
      #pragma unroll
      for (int ks = 0; ks < 4; ++ks)
        af[mt][ks] = *(const s16x8*)(Xb + (size_t)(rb + mt * 16 + l15) * 128 + ks * 32 + g * 8);
    f32x4 acc[4][4];
    #pragma unroll
    for (int mt = 0; mt < 4; ++mt)
      #pragma unroll
      for (int nt = 0; nt < 4; ++nt) acc[mt][nt] = f32x4{0.f,0.f,0.f,0.f};
    #pragma unroll
    for (int ks = 0; ks < 4; ++ks)
      #pragma unroll
      for (int nt = 0; nt < 4; ++nt)
        #pragma unroll
        for (int mt = 0; mt < 4; ++mt)
          acc[mt][nt] = mfma16(af[mt][ks], wf[nt][ks], acc[mt][nt]);
    #pragma unroll
    for (int mt = 0; mt < 4; ++mt){
      f32x4 s4 = {0.f,0.f,0.f,0.f}, q4 = {0.f,0.f,0.f,0.f};
      #pragma unroll
      for (int nt = 0; nt < 4; ++nt){
        f32x4 t = acc[mt][nt] + br[nt];
        s4 += t; q4 += t * t;
      }
      #pragma unroll
      for (int j = 0; j < 4; ++j){
        float ss = dpp_reduce16(s4[j]);
        float qq = dpp_reduce16(q4[j]);
        if (l15 == 0){
          sstat[wid][mt * 16 + g * 4 + j][0] = ss;
          sstat[wid][mt * 16 + g * 4 + j][1] = qq;
        }
      }
    }
    __syncthreads();
    if (wid == 0){
      int row = rb + lane;
      float sK = sstat[0][lane][0] + sstat[1][lane][0];
      float qK = sstat[0][lane][1] + sstat[1][lane][1];
      float sV = sstat[2][lane][0] + sstat[3][lane][0];
      float qV = sstat[2][lane][1] + sstat[3][lane][1];
      float muK = sK * 0.0078125f, muV = sV * 0.0078125f;
      float aa = rsqrtf(qK * 0.0078125f - muK * muK + 1e-5f);
      float bb = rsqrtf(qV * 0.0078125f - muV * muV + 1e-5f);
      aFb[row] = aa; bFb[row] = bb; cFb[row] = aa * bb;
    }
    __syncthreads();
  }
}

// ---------- kS2: Spart[bh][grp] += [cX;c;a;b]^T [X|1]  (no barriers) ----------
__global__ __launch_bounds__(512, 2) void kS2(
    const u16* __restrict__ XTF, const float* __restrict__ aF,
    const float* __restrict__ bF, const float* __restrict__ cF,
    float* __restrict__ Spart)
{
  const int tid = threadIdx.x, wid = tid >> 6, lane = tid & 63, g = lane >> 4, l15 = lane & 15;
  const int bh = blockIdx.x >> 4, grp = blockIdx.x & 15;
  const int b = bh >> 3;
  const int mtp = wid & 3, nth = wid >> 2;
  const u16* xtb = XTF + (size_t)b * 4194304;
  const float* cFb = cF + (size_t)bh * 32768;
  const float* aFb = aF + (size_t)bh * 32768;
  const float* bFb = bF + (size_t)bh * 32768;

  f32x4 accC[2][4], accB[2], accS = {0.f,0.f,0.f,0.f}, accS8 = {0.f,0.f,0.f,0.f};
  #pragma unroll
  for (int m2 = 0; m2 < 2; ++m2){
    accB[m2] = f32x4{0.f,0.f,0.f,0.f};
    #pragma unroll
    for (int q = 0; q < 4; ++q) accC[m2][q] = f32x4{0.f,0.f,0.f,0.f};
  }
  s16x8 bone;
  { u32 o = (l15 == 0) ? 0x3F803F80u : 0u; u32x4 t = {o, o, o, o};
    bone = __builtin_bit_cast(s16x8, t); }

#define LOADK(kst, S) { \
    const int lcg_ = grp * 64 + (kst); \
    const size_t base_ = (size_t)(lcg_ * 4 + g) * 128 + (size_t)l15 * 8; \
    xa0##S = *(const s16x8*)(xtb + (size_t)(2*mtp+0) * 524288 + base_); \
    xa1##S = *(const s16x8*)(xtb + (size_t)(2*mtp+1) * 524288 + base_); \
    xb0##S = *(const s16x8*)(xtb + (size_t)(4*nth+0) * 524288 + base_); \
    xb1##S = *(const s16x8*)(xtb + (size_t)(4*nth+1) * 524288 + base_); \
    xb2##S = *(const s16x8*)(xtb + (size_t)(4*nth+2) * 524288 + base_); \
    xb3##S = *(const s16x8*)(xtb + (size_t)(4*nth+3) * 524288 + base_); \
    const float* cp_ = cFb + lcg_ * 32 + g * 8; \
    c0##S = *(const float4*)cp_; c1##S = *(const float4*)(cp_ + 4); \
    const float* ap_ = aFb + lcg_ * 32 + g * 8; \
    a0##S = *(const float4*)ap_; a1##S = *(const float4*)(ap_ + 4); \
    const float* bp_ = bFb + lcg_ * 32 + g * 8; \
    b0##S = *(const float4*)bp_; b1##S = *(const float4*)(bp_ + 4); \
  }

#define COMP(S) { \
    float cs_[8] = {c0##S.x, c0##S.y, c0##S.z, c0##S.w, c1##S.x, c1##S.y, c1##S.z, c1##S.w}; \
    s16x8 aS0, aS1; \
    { float fa[8]; unpack8(xa0##S, fa); \
      u32x4 pv = {cvtpk(fa[0]*cs_[0], fa[1]*cs_[1]), cvtpk(fa[2]*cs_[2], fa[3]*cs_[3]), \
                  cvtpk(fa[4]*cs_[4], fa[5]*cs_[5]), cvtpk(fa[6]*cs_[6], fa[7]*cs_[7])}; \
      aS0 = __builtin_bit_cast(s16x8, pv); } \
    { float fa[8]; unpack8(xa1##S, fa); \
      u32x4 pv = {cvtpk(fa[0]*cs_[0], fa[1]*cs_[1]), cvtpk(fa[2]*cs_[2], fa[3]*cs_[3]), \
                  cvtpk(fa[4]*cs_[4], fa[5]*cs_[5]), cvtpk(fa[6]*cs_[6], fa[7]*cs_[7])}; \
      aS1 = __builtin_bit_cast(s16x8, pv); } \
    u32x4 pc_ = {cvtpk(c0##S.x, c0##S.y), cvtpk(c0##S.z, c0##S.w), cvtpk(c1##S.x, c1##S.y), cvtpk(c1##S.z, c1##S.w)}; \
    u32x4 pa_ = {cvtpk(a0##S.x, a0##S.y), cvtpk(a0##S.z, a0##S.w), cvtpk(a1##S.x, a1##S.y), cvtpk(a1##S.z, a1##S.w)}; \
    u32x4 pb_ = {cvtpk(b0##S.x, b0##S.y), cvtpk(b0##S.z, b0##S.w), cvtpk(b1##S.x, b1##S.y), cvtpk(b1##S.z, b1##S.w)}; \
    u32x4 ps_ = {0,0,0,0}; \
    if (l15 == 0) ps_ = pc_; else if (l15 == 1) ps_ = pa_; else if (l15 == 2) ps_ = pb_; \
    s16x8 astr = __builtin_bit_cast(s16x8, ps_); \
    accC[0][0] = mfma16(aS0, xb0##S, accC[0][0]); accC[1][0] = mfma16(aS1, xb0##S, accC[1][0]); \
    accC[0][1] = mfma16(aS0, xb1##S, accC[0][1]); accC[1][1] = mfma16(aS1, xb1##S, accC[1][1]); \
    accC[0][2] = mfma16(aS0, xb2##S, accC[0][2]); accC[1][2] = mfma16(aS1, xb2##S, accC[1][2]); \
    accC[0][3] = mfma16(aS0, xb3##S, accC[0][3]); accC[1][3] = mfma16(aS1, xb3##S, accC[1][3]); \
    s16x8 bsel = (mtp == 0) ? xb0##S : (mtp == 1) ? xb1##S : (mtp == 2) ? xb2##S : xb3##S; \
    accS = mfma16(astr, bsel, accS); \
    if (nth == 0){ \
      accB[0] = mfma16(aS0, bone, accB[0]); \
      accB[1] = mfma16(aS1, bone, accB[1]); \
      if (wid == 0) accS8 = mfma16(astr, bone, accS8); \
    } \
  }

  s16x8 xa0A, xa1A, xb0A, xb1A, xb2A, xb3A;
  s16x8 xa0B, xa1B, xb0B, xb1B, xb2B, xb3B;
  float4 c0A, c1A, a0A, a1A, b0A, b1A;
  float4 c0B, c1B, a0B, a1B, b0B, b1B;

  LOADK(0, A);
  #pragma unroll 1
  for (int kst = 0; kst < 64; kst += 2){
    LOADK(kst + 1, B);
    COMP(A);
    if (kst + 2 < 64){ LOADK(kst + 2, A); }
    COMP(B);
  }
#undef COMP
#undef LOADK

  float* Sp = Spart + ((size_t)bh * 16 + grp) * 19008;   // 132*144
  #pragma unroll
  for (int m2 = 0; m2 < 2; ++m2)
    #pragma unroll
    for (int q = 0; q < 4; ++q)
      #pragma unroll
      for (int j = 0; j < 4; ++j)
        Sp[((2*mtp + m2)*16 + g*4 + j) * 144 + (4*nth + q)*16 + l15] = accC[m2][q][j];
  if (g == 0){
    #pragma unroll
    for (int j = 0; j < 3; ++j)
      Sp[(128 + j) * 144 + wid * 16 + l15] = accS[j];
  }
  if (nth == 0 && l15 == 0){
    #pragma unroll
    for (int m2 = 0; m2 < 2; ++m2)
      #pragma unroll
      for (int j = 0; j < 4; ++j)
        Sp[((2*mtp + m2)*16 + g*4 + j) * 144 + 128] = accB[m2][j];
  }
  if (wid == 0 && g == 0 && l15 == 0){
    #pragma unroll
    for (int j = 0; j < 3; ++j)
      Sp[(128 + j) * 144 + 128] = accS8[j];
  }
}

// ---------- kred: S = sum over grp of Spart ----------
__global__ __launch_bounds__(256) void kred(const float* __restrict__ Spart, float* __restrict__ S){
  int bh = blockIdx.x, r = blockIdx.y, c = threadIdx.x;
  if (c >= 144) return;
  float s = 0.f;
  const float* p = Spart + (size_t)bh * 16 * 19008 + r * 144 + c;
  #pragma unroll
  for (int gq = 0; gq < 16; ++gq) s += p[(size_t)gq * 19008];
  S[(size_t)bh * 19008 + r * 144 + c] = s;
}

// ---------- kfoldA: G = W~k^T S2 W~v + rank1 + LN gamma/beta corrections -> AM ----------
__global__ __launch_bounds__(256) void kfoldA(
    const float* __restrict__ S, const float* __restrict__ Wk, const float* __restrict__ Wv,
    const float* __restrict__ Wkb, const float* __restrict__ Wvb,
    const float* __restrict__ w1u, const float* __restrict__ scn,
    const float* __restrict__ gk, const float* __restrict__ bbk,
    const float* __restrict__ gv, const float* __restrict__ bbv,
    float* __restrict__ AM)
{
  extern __shared__ float fsm[];
  float* sA = fsm;                 // [128][129]
  float* sS = fsm + 16512;         // [128][33]
  float* svt = fsm + 20736;        // [32]
  float* svb = fsm + 20768;        // [32]
  float* skt = fsm + 20800;        // [128]
  float* skb = fsm + 20928;        // [128]
  const int blk = blockIdx.x, bh = blk >> 2, es = blk & 3;
  const int h = bh & 7;
  const int tid = threadIdx.x;
  const float* Sg = S + (size_t)bh * 19008;
  const float mbk = scn[h], mbv = scn[8 + h];

  for (int idx = tid; idx < 16384; idx += 256){
    int r = idx >> 7, c = idx & 127;
    sA[r * 129 + c] = Sg[r * 144 + c];
  }
  for (int idx = tid; idx < 4096; idx += 256){
    int c = idx >> 5, j = idx & 31;
    sS[c * 33 + j] = Wv[(size_t)c * 1024 + h * 128 + es * 32 + j] - w1u[(8 + h) * 128 + c];
  }
  __syncthreads();
  if (tid < 32){
    float t = 0.f, tb = 0.f;
    for (int c = 0; c < 128; ++c){
      float wv = sS[c * 33 + tid];
      t  += Sg[128 * 144 + c] * wv;
      tb += Sg[130 * 144 + c] * wv;
    }
    svt[tid] = t;
    svb[tid] = tb + Sg[130 * 144 + 128] * (Wvb[h * 128 + es * 32 + tid] - mbv);
  }
  const int r0 = (tid >> 4) * 8, e0 = (tid & 15) * 2;
  float t8[8][2] = {};
  for (int c = 0; c < 128; ++c){
    float w0 = sS[c * 33 + e0], w1_ = sS[c * 33 + e0 + 1];
    #pragma unroll
    for (int i = 0; i < 8; ++i){
      float a = sA[(r0 + i) * 129 + c];
      t8[i][0] += a * w0; t8[i][1] += a * w1_;
    }
  }
  __syncthreads();
  #pragma unroll
  for (int i = 0; i < 8; ++i){
    sS[(r0 + i) * 33 + e0] = t8[i][0];
    sS[(r0 + i) * 33 + e0 + 1] = t8[i][1];
  }
  for (int idx = tid; idx < 16384; idx += 256){
    int c = idx >> 7, n = idx & 127;
    sA[c * 129 + n] = Wk[(size_t)c * 1024 + h * 128 + n] - w1u[h * 128 + c];
  }
  __syncthreads();
  if (tid < 128){
    float t = 0.f, ta = 0.f;
    for (int c = 0; c < 128; ++c){
      float wk = sA[c * 129 + tid];
      t  += Sg[128 * 144 + c] * wk;
      ta += Sg[129 * 144 + c] * wk;
    }
    skt[tid] = t;
    skb[tid] = ta + Sg[129 * 144 + 128] * (Wkb[h * 128 + tid] - mbk);
  }
  float g8[8][2] = {};
  for (int c = 0; c < 128; ++c){
    float t0 = sS[c * 33 + e0], t1 = sS[c * 33 + e0 + 1];
    #pragma unroll
    for (int i = 0; i < 8; ++i){
      float wk = sA[c * 129 + (r0 + i)];
      g8[i][0] += wk * t0; g8[i][1] += wk * t1;
    }
  }
  __syncthreads();
  const float s0 = Sg[128 * 144 + 128];
  #pragma unroll
  for (int i = 0; i < 8; ++i){
    int n = r0 + i;
    float btk = Wkb[h * 128 + n] - mbk;
    #pragma unroll
    for (int jj = 0; jj < 2; ++jj){
      int j = e0 + jj, dv = es * 32 + j;
      float btv = Wvb[h * 128 + dv] - mbv;
      float G = g8[i][jj] + skt[n] * btv + btk * svt[j] + s0 * btk * btv;
      float am = gk[h*128+n] * (gv[h*128+dv] * G + skb[n] * bbv[h*128+dv])
               + bbk[h*128+n] * (gv[h*128+dv] * svb[j] + 32768.f * bbv[h*128+dv]);
      AM[(size_t)bh * 16384 + n * 128 + dv] = am;
    }
  }
}

// ---------- kfoldB: T1 = AM@Wo ; W4F += frag(Wq@T1)/n ; c4 ----------
__global__ __launch_bounds__(256) void kfoldB(
    const float* __restrict__ AM, const float* __restrict__ Wo,
    const float* __restrict__ Wq, const float* __restrict__ Wq_b,
    const float* __restrict__ Wo_b, float* __restrict__ W4F, float* __restrict__ c4)
{
  extern __shared__ float fsm[];
  float* sA = fsm;
  float* sS = fsm + 128 * 129;
  int blk = blockIdx.x;
  int bh = blk >> 2, eq = blk & 3;
  int b = bh >> 3, hs = bh & 7;
  int tid = threadIdx.x;

  for (int idx = tid; idx < 16384; idx += 256){
    int r = idx >> 7, c = idx & 127;
    sA[r * 129 + c] = AM[(size_t)bh * 16384 + idx];
  }
  for (int idx = tid; idx < 4096; idx += 256){
    int r = idx >> 5, c = idx & 31;
    sS[r * 33 + c] = Wo[(size_t)hs * 16384 + r * 128 + eq * 32 + c];
  }
  __syncthreads();

  int r0 = (tid >> 4) * 8, e0 = (tid & 15) * 2;
  float t8[8][2] = {};
  for (int c = 0; c < 128; ++c){
    float wv0 = sS[c * 33 + e0], wv1 = sS[c * 33 + e0 + 1];
    #pragma unroll
    for (int i = 0; i < 8; ++i){
      float a = sA[(r0 + i) * 129 + c];
      t8[i][0] += a * wv0; t8[i][1] += a * wv1;
    }
  }
  __syncthreads();
  #pragma unroll
  for (int i = 0; i < 8; ++i){
    sS[(r0 + i) * 33 + e0]     = t8[i][0];
    sS[(r0 + i) * 33 + e0 + 1] = t8[i][1];
  }
  for (int idx = tid; idx < 16384; idx += 256){
    int r = idx >> 7, c = idx & 127;
    sA[r * 129 + c] = Wq[(size_t)r * 1024 + hs * 128 + c];
  }
  __syncthreads();

  float a8[8][2] = {};
  for (int d = 0; d < 128; ++d){
    float t0 = sS[d * 33 + e0], t1 = sS[d * 33 + e0 + 1];
    #pragma unroll
    for (int i = 0; i < 8; ++i){
      float w = sA[(r0 + i) * 129 + d];
      a8[i][0] += w * t0; a8[i][1] += w * t1;
    }
  }
  const float inv_n = 0.0009765625f;
  #pragma unroll
  for (int i = 0; i < 8; ++i)
    #pragma unroll
    for (int j = 0; j < 2; ++j){
      int cc = r0 + i, nn = eq * 32 + e0 + j;
      int o = ((nn >> 4) * 4 + (cc >> 5)) * 512 + ((cc >> 3) & 3) * 128
            + (nn & 15) * 8 + (cc & 7);
      atomicAdd(W4F + (size_t)b * 16384 + o, a8[i][j] * inv_n);
    }
  if (tid < 32){
    float s = 0.f;
    for (int d = 0; d < 128; ++d) s += Wq_b[hs * 128 + d] * sS[d * 33 + tid];
    if (hs == 0) s += Wo_b[eq * 32 + tid];
    atomicAdd(c4 + b * 128 + eq * 32 + tid, s * inv_n);
  }
}

// ---------- kout = x @ W4[b] + c4[b] ----------
__global__ __launch_bounds__(256, 4) void kout(
    const u16* __restrict__ X, const float* __restrict__ W4F,
    const float* __restrict__ c4, float* __restrict__ out)
{
  __shared__ char sW[32768];
  const int tid = threadIdx.x, wid = tid >> 6, lane = tid & 63, g = lane >> 4, l15 = lane & 15;
  const int blk = blockIdx.x, b = blk >> 8, ch = blk & 255;
  {
    const float* w4b = W4F + (size_t)b * 16384;
    #pragma unroll
    for (int it2 = 0; it2 < 16; ++it2){
      int idx = it2 * 1024 + tid * 4;
      float4 f = *(const float4*)(w4b + idx);
      uint2 w; w.x = cvtpk(f.x, f.y); w.y = cvtpk(f.z, f.w);
      *(uint2*)(sW + idx * 2) = w;
    }
  }
  const char* xr = (const char*)(X + ((size_t)b * 32768 + ch * 128 + wid * 32 + l15) * 128) + g * 16;
  s16x8 af[2][4];
  #pragma unroll
  for (int mt = 0; mt < 2; ++mt)
    #pragma unroll
    for (int ks = 0; ks < 4; ++ks)
      af[mt][ks] = *(const s16x8*)(xr + mt * 4096 + ks * 64);
  __syncthreads();

  f32x4 acc[2][8];
  #pragma unroll
  for (int mt = 0; mt < 2; ++mt)
    #pragma unroll
    for (int nt = 0; nt < 8; ++nt) acc[mt][nt] = f32x4{0.f, 0.f, 0.f, 0.f};

  const u32 wread = (u32)(lane * 16);
  #pragma unroll
  for (int ks = 0; ks < 4; ++ks)
    #pragma unroll
    for (int nt = 0; nt < 8; ++nt){
      s16x8 wf = *(const s16x8*)(sW + wread + (nt * 4 + ks) * 1024);
      acc[0][nt] = mfma16(af[0][ks], wf, acc[0][nt]);
      acc[1][nt] = mfma16(af[1][ks], wf, acc[1][nt]);
    }
  float* ob = out + ((size_t)b * 32768 + ch * 128 + wid * 32) * 128;
  #pragma unroll
  for (int nt = 0; nt < 8; ++nt){
    float c4v = c4[b * 128 + nt * 16 + l15];
    #pragma unroll
    for (int mt = 0; mt < 2; ++mt)
      #pragma unroll
      for (int j = 0; j < 4; ++j)
        ob[(mt * 16 + g * 4 + j) * 128 + nt * 16 + l15] = acc[mt][nt][j] + c4v;
  }
}

extern "C" void kernel_launch(void* const* d_in, const int* in_sizes, int n_in,
                              void* d_out, int out_size, void* d_ws, size_t ws_size,
                              hipStream_t stream){
  const float* v    = (const float*)d_in[0];
  const float* Wq_w = (const float*)d_in[1];
  const float* Wq_b = (const float*)d_in[2];
  const float* Wk_w = (const float*)d_in[3];
  const float* Wk_b = (const float*)d_in[4];
  const float* Wv_w = (const float*)d_in[5];
  const float* Wv_b = (const float*)d_in[6];
  const float* Wo_w = (const float*)d_in[7];
  const float* Wo_b = (const float*)d_in[8];
  const float* lnk_g = (const float*)d_in[9];
  const float* lnk_b = (const float*)d_in[10];
  const float* lnv_g = (const float*)d_in[11];
  const float* lnv_b = (const float*)d_in[12];

  char* ws = (char*)d_ws;
  u16*   X     = (u16*)  (ws);                 // 16,777,216
  u16*   XTF   = (u16*)  (ws + 16777216);      // 16,777,216
  u16*   WF    = (u16*)  (ws + 33554432);      // 524,288
  float* cF    = (float*)(ws + 34078720);      // 2,097,152
  float* aF    = (float*)(ws + 36175872);      // 2,097,152
  float* bF    = (float*)(ws + 38273024);      // 2,097,152
  float* w1u   = (float*)(ws + 40370176);      // 8,192
  float* scn   = (float*)(ws + 40378368);      // 128
  float* Spart = (float*)(ws + 40378496);      // 19,464,192
  float* S     = (float*)(ws + 59842688);      // 1,216,512
  float* AM    = (float*)(ws + 61059200);      // 1,048,576
  float* W4F   = (float*)(ws + 62107776);      // 131,072
  float* c4    = (float*)(ws + 62238848);      // 1,024

  hipMemsetAsync(ws + 62107776, 0, 132096, stream);   // W4F + c4

  hipLaunchKernelGGL(kprep, dim3(528), dim3(256), 0, stream,
                     v, Wk_w, Wv_w, Wk_b, Wv_b, X, XTF, WF, w1u, scn);

  hipLaunchKernelGGL(kstat, dim3(512), dim3(256), 0, stream,
                     X, WF, Wk_b, Wv_b, aF, bF, cF);

  hipLaunchKernelGGL(kS2, dim3(256), dim3(512), 0, stream, XTF, aF, bF, cF, Spart);

  hipLaunchKernelGGL(kred, dim3(16, 132), dim3(256), 0, stream, Spart, S);

  (void)hipFuncSetAttribute((const void*)kfoldA,
                            hipFuncAttributeMaxDynamicSharedMemorySize, 84224);
  hipLaunchKernelGGL(kfoldA, dim3(64), dim3(256), 84224, stream,
                     S, Wk_w, Wv_w, Wk_b, Wv_b, w1u, scn,
                     lnk_g, lnk_b, lnv_g, lnv_b, AM);

  (void)hipFuncSetAttribute((const void*)kfoldB,
                            hipFuncAttributeMaxDynamicSharedMemorySize, 82944);
  hipLaunchKernelGGL(kfoldB, dim3(64), dim3(256), 82944, stream,
                     AM, Wo_w, Wq_w, Wq_b, Wo_b, W4F, c4);

  hipLaunchKernelGGL(kout, dim3(512), dim3(256), 0, stream, X, W4F, c4, (float*)d_out);
}

// Round 8
// 215.090 us; speedup vs baseline: 1.2807x; 1.1279x over previous
//
#include <hip/hip_runtime.h>
#include <stdint.h>

typedef unsigned short u16;
typedef unsigned int u32;
typedef __attribute__((ext_vector_type(8))) short s16x8;
typedef __attribute__((ext_vector_type(8))) __bf16 bf16x8;
typedef __attribute__((ext_vector_type(4))) float f32x4;
typedef __attribute__((ext_vector_type(4))) u32 u32x4;
typedef __attribute__((ext_vector_type(4))) u16 u16x4;

__device__ __forceinline__ u32 f2bf(float f){
  u32 u = __builtin_bit_cast(u32, f);
  return (u + 0x7FFFu + ((u >> 16) & 1u)) >> 16;
}

__device__ __forceinline__ f32x4 mfma16(s16x8 a, s16x8 b, f32x4 c){
  return __builtin_amdgcn_mfma_f32_16x16x32_bf16(
      __builtin_bit_cast(bf16x8, a), __builtin_bit_cast(bf16x8, b), c, 0, 0, 0);
}

__device__ __forceinline__ u32 cvtpk(float lo, float hi){
  u32 r;
  asm("v_cvt_pk_bf16_f32 %0, %1, %2" : "=v"(r) : "v"(lo), "v"(hi));
  return r;
}

__device__ __forceinline__ float dpp_reduce16(float x){
  float y;
  asm("v_add_f32_dpp %0, %1, %1 row_ror:8 row_mask:0xf bank_mask:0xf"
      : "=&v"(y) : "v"(x));
  asm("v_add_f32_dpp %0, %1, %1 row_ror:4 row_mask:0xf bank_mask:0xf"
      : "=&v"(x) : "v"(y));
  asm("v_add_f32_dpp %0, %1, %1 quad_perm:[2,3,0,1] row_mask:0xf bank_mask:0xf"
      : "=&v"(y) : "v"(x));
  asm("v_add_f32_dpp %0, %1, %1 quad_perm:[1,0,3,2] row_mask:0xf bank_mask:0xf"
      : "=&v"(x) : "v"(y));
  return x;
}

__device__ __forceinline__ void unpack8(s16x8 v, float* f){
  u32x4 u = __builtin_bit_cast(u32x4, v);
  #pragma unroll
  for (int i = 0; i < 4; ++i){
    f[2*i]   = __builtin_bit_cast(float, u[i] << 16);
    f[2*i+1] = __builtin_bit_cast(float, u[i] & 0xffff0000u);
  }
}

// ---------- kprep: X bf16, XTF (transposed frag layout), WF frags, w1/mb ----------
// XTF[b][ct 8][lcg 1024][g 4][l15 16][e 8] = x[row=lcg*32+g*8+e][col=ct*16+l15]
__global__ __launch_bounds__(256) void kprep(
    const float* __restrict__ v, const float* __restrict__ Wk, const float* __restrict__ Wv,
    const float* __restrict__ Wkb, const float* __restrict__ Wvb,
    u16* __restrict__ X, u16* __restrict__ XTF, u16* __restrict__ WF,
    float* __restrict__ w1u, float* __restrict__ scn)
{
  const int tid = threadIdx.x;
  if (blockIdx.x < 512){
    __shared__ u16 sx[128 * 132];
    const int blk = blockIdx.x, b = blk >> 8, lch = blk & 255;
    const float* vb = v + ((size_t)b * 32768 + lch * 128) * 128;
    u16* xb = X + ((size_t)b * 32768 + lch * 128) * 128;
    #pragma unroll
    for (int i = 0; i < 16; ++i){
      int flat = i * 1024 + tid * 4;
      int r = flat >> 7, c = flat & 127;
      float4 f = *(const float4*)(vb + flat);
      u16x4 o; o.x = (u16)f2bf(f.x); o.y = (u16)f2bf(f.y); o.z = (u16)f2bf(f.z); o.w = (u16)f2bf(f.w);
      *(u16x4*)(xb + flat) = o;
      *(u16x4*)(&sx[r * 132 + c]) = o;
    }
    __syncthreads();
    #pragma unroll
    for (int it = 0; it < 8; ++it){
      int t = it * 256 + tid;
      int l15 = t & 15, gg = (t >> 4) & 3, lc = (t >> 6) & 3, ct = t >> 8;
      u16 tmp[8];
      #pragma unroll
      for (int e = 0; e < 8; ++e)
        tmp[e] = sx[(lc * 32 + gg * 8 + e) * 132 + ct * 16 + l15];
      u32 w0 = (u32)tmp[0] | ((u32)tmp[1] << 16);
      u32 w1_ = (u32)tmp[2] | ((u32)tmp[3] << 16);
      u32 w2 = (u32)tmp[4] | ((u32)tmp[5] << 16);
      u32 w3 = (u32)tmp[6] | ((u32)tmp[7] << 16);
      u32x4 uu = {w0, w1_, w2, w3};
      size_t off = ((((size_t)b * 8 + ct) * 1024 + (lch * 4 + lc)) * 4 + gg) * 128 + (size_t)l15 * 8;
      *reinterpret_cast<u32x4*>(XTF + off) = uu;
    }
  } else {
    const int hp = blockIdx.x - 512, h = hp & 7, proj = hp >> 3;
    const float* W = proj ? Wv : Wk;
    const float* pb = (proj ? Wvb : Wkb) + h * 128;
    for (int i = tid; i < 16384; i += 256){
      int e = i & 7, ln = (i >> 3) & 63, ks = (i >> 9) & 3, nt = i >> 11;
      int c = ks * 32 + (ln >> 4) * 8 + e;
      int n = nt * 16 + (ln & 15);
      WF[proj * 131072 + h * 16384 + i] = (u16)f2bf(W[(size_t)c * 1024 + h * 128 + n]);
    }
    if (tid < 128){
      float s = 0.f;
      const float* p = W + (size_t)tid * 1024 + h * 128;
      for (int n = 0; n < 128; ++n) s += p[n];
      w1u[hp * 128 + tid] = s * 0.0078125f;
    }
    if (tid == 0){
      float mb = 0.f;
      for (int n = 0; n < 128; ++n) mb += pb[n];
      scn[hp] = mb * 0.0078125f;
    }
  }
}

// ---------- kstat v3: barrier-free. Each wave: full-row proj (weights in 128 VGPR),
// 16 rows/iter, stats close in-wave via dpp. Waves 0-3: K -> aF; 4-7: V -> bF. ----------
__global__ __launch_bounds__(512, 2) void kstat(
    const u16* __restrict__ X, const u16* __restrict__ WF,
    const float* __restrict__ bk, const float* __restrict__ bv,
    float* __restrict__ aF, float* __restrict__ bF)
{
  const int tid = threadIdx.x, wid = tid >> 6, lane = tid & 63, g = lane >> 4, l15 = lane & 15;
  const int bh = blockIdx.x >> 5, grp = blockIdx.x & 31;
  const int b = bh >> 3, h = bh & 7;
  const int proj = wid >> 2, w4 = wid & 3;

  s16x8 wf[8][4];
  {
    const u16* wbase = WF + proj * 131072 + h * 16384;
    #pragma unroll
    for (int nt = 0; nt < 8; ++nt)
      #pragma unroll
      for (int ks = 0; ks < 4; ++ks)
        wf[nt][ks] = *(const s16x8*)(wbase + (size_t)((nt * 4 + ks) * 512) + lane * 8);
  }
  const float* bias = proj ? bv : bk;
  float br[8];
  #pragma unroll
  for (int nt = 0; nt < 8; ++nt) br[nt] = bias[h * 128 + nt * 16 + l15];

  const u16* Xb = X + (size_t)b * 32768 * 128;
  float* oF = (proj ? bF : aF) + (size_t)bh * 32768;
  const int rb0 = grp * 1024 + w4 * 256;

  s16x8 af[4], afn[4];
  #pragma unroll
  for (int ks = 0; ks < 4; ++ks)
    af[ks] = *(const s16x8*)(Xb + (size_t)(rb0 + l15) * 128 + ks * 32 + g * 8);

  #pragma unroll 1
  for (int it = 0; it < 16; ++it){
    const int rb = rb0 + it * 16;
    // prefetch next 16 rows (last iter reads 16 rows past range; safely inside d_ws)
    #pragma unroll
    for (int ks = 0; ks < 4; ++ks)
      afn[ks] = *(const s16x8*)(Xb + (size_t)(rb + 16 + l15) * 128 + ks * 32 + g * 8);
    f32x4 acc[8];
    #pragma unroll
    for (int nt = 0; nt < 8; ++nt) acc[nt] = f32x4{0.f,0.f,0.f,0.f};
    #pragma unroll
    for (int ks = 0; ks < 4; ++ks)
      #pragma unroll
      for (int nt = 0; nt < 8; ++nt)
        acc[nt] = mfma16(af[ks], wf[nt][ks], acc[nt]);
    f32x4 s4 = {0.f,0.f,0.f,0.f}, q4 = {0.f,0.f,0.f,0.f};
    #pragma unroll
    for (int nt = 0; nt < 8; ++nt){
      f32x4 t = acc[nt] + br[nt];
      s4 += t; q4 += t * t;
    }
    #pragma unroll
    for (int j = 0; j < 4; ++j){
      float ss = dpp_reduce16(s4[j]);
      float qq = dpp_reduce16(q4[j]);
      float mu = ss * 0.0078125f;
      float var = qq * 0.0078125f - mu * mu;
      float rs = rsqrtf(var + 1e-5f);
      if (l15 == g * 4 + j) oF[rb + l15] = rs;
    }
    #pragma unroll
    for (int ks = 0; ks < 4; ++ks) af[ks] = afn[ks];
  }
}

// ---------- kS2: atomicAdd S[bh] += [cX;c;a;b]^T [X|1]  (c = a*b in-reg) ----------
__global__ __launch_bounds__(512, 2) void kS2(
    const u16* __restrict__ XTF, const float* __restrict__ aF,
    const float* __restrict__ bF, float* __restrict__ S)
{
  const int tid = threadIdx.x, wid = tid >> 6, lane = tid & 63, g = lane >> 4, l15 = lane & 15;
  const int bh = blockIdx.x >> 4, grp = blockIdx.x & 15;
  const int b = bh >> 3;
  const int mtp = wid & 3, nth = wid >> 2;
  const u16* xtb = XTF + (size_t)b * 4194304;
  const float* aFb = aF + (size_t)bh * 32768;
  const float* bFb = bF + (size_t)bh * 32768;

  f32x4 accC[2][4], accB[2], accS = {0.f,0.f,0.f,0.f}, accS8 = {0.f,0.f,0.f,0.f};
  #pragma unroll
  for (int m2 = 0; m2 < 2; ++m2){
    accB[m2] = f32x4{0.f,0.f,0.f,0.f};
    #pragma unroll
    for (int q = 0; q < 4; ++q) accC[m2][q] = f32x4{0.f,0.f,0.f,0.f};
  }
  s16x8 bone;
  { u32 o = (l15 == 0) ? 0x3F803F80u : 0u; u32x4 t = {o, o, o, o};
    bone = __builtin_bit_cast(s16x8, t); }

#define LOADK(kst, Sx) { \
    const int lcg_ = grp * 64 + (kst); \
    const size_t base_ = (size_t)(lcg_ * 4 + g) * 128 + (size_t)l15 * 8; \
    xa0##Sx = *(const s16x8*)(xtb + (size_t)(2*mtp+0) * 524288 + base_); \
    xa1##Sx = *(const s16x8*)(xtb + (size_t)(2*mtp+1) * 524288 + base_); \
    xb0##Sx = *(const s16x8*)(xtb + (size_t)(4*nth+0) * 524288 + base_); \
    xb1##Sx = *(const s16x8*)(xtb + (size_t)(4*nth+1) * 524288 + base_); \
    xb2##Sx = *(const s16x8*)(xtb + (size_t)(4*nth+2) * 524288 + base_); \
    xb3##Sx = *(const s16x8*)(xtb + (size_t)(4*nth+3) * 524288 + base_); \
    const float* ap_ = aFb + lcg_ * 32 + g * 8; \
    a0##Sx = *(const f32x4*)ap_; a1##Sx = *(const f32x4*)(ap_ + 4); \
    const float* bp_ = bFb + lcg_ * 32 + g * 8; \
    b0##Sx = *(const f32x4*)bp_; b1##Sx = *(const f32x4*)(bp_ + 4); \
  }

#define COMP(Sx) { \
    f32x4 c0_ = a0##Sx * b0##Sx, c1_ = a1##Sx * b1##Sx; \
    float cs_[8] = {c0_.x, c0_.y, c0_.z, c0_.w, c1_.x, c1_.y, c1_.z, c1_.w}; \
    s16x8 aS0, aS1; \
    { float fa[8]; unpack8(xa0##Sx, fa); \
      u32x4 pv = {cvtpk(fa[0]*cs_[0], fa[1]*cs_[1]), cvtpk(fa[2]*cs_[2], fa[3]*cs_[3]), \
                  cvtpk(fa[4]*cs_[4], fa[5]*cs_[5]), cvtpk(fa[6]*cs_[6], fa[7]*cs_[7])}; \
      aS0 = __builtin_bit_cast(s16x8, pv); } \
    { float fa[8]; unpack8(xa1##Sx, fa); \
      u32x4 pv = {cvtpk(fa[0]*cs_[0], fa[1]*cs_[1]), cvtpk(fa[2]*cs_[2], fa[3]*cs_[3]), \
                  cvtpk(fa[4]*cs_[4], fa[5]*cs_[5]), cvtpk(fa[6]*cs_[6], fa[7]*cs_[7])}; \
      aS1 = __builtin_bit_cast(s16x8, pv); } \
    u32x4 pc_ = {cvtpk(c0_.x, c0_.y), cvtpk(c0_.z, c0_.w), cvtpk(c1_.x, c1_.y), cvtpk(c1_.z, c1_.w)}; \
    u32x4 pa_ = {cvtpk(a0##Sx.x, a0##Sx.y), cvtpk(a0##Sx.z, a0##Sx.w), cvtpk(a1##Sx.x, a1##Sx.y), cvtpk(a1##Sx.z, a1##Sx.w)}; \
    u32x4 pb_ = {cvtpk(b0##Sx.x, b0##Sx.y), cvtpk(b0##Sx.z, b0##Sx.w), cvtpk(b1##Sx.x, b1##Sx.y), cvtpk(b1##Sx.z, b1##Sx.w)}; \
    u32x4 ps_ = {0,0,0,0}; \
    if (l15 == 0) ps_ = pc_; else if (l15 == 1) ps_ = pa_; else if (l15 == 2) ps_ = pb_; \
    s16x8 astr = __builtin_bit_cast(s16x8, ps_); \
    accC[0][0] = mfma16(aS0, xb0##Sx, accC[0][0]); accC[1][0] = mfma16(aS1, xb0##Sx, accC[1][0]); \
    accC[0][1] = mfma16(aS0, xb1##Sx, accC[0][1]); accC[1][1] = mfma16(aS1, xb1##Sx, accC[1][1]); \
    accC[0][2] = mfma16(aS0, xb2##Sx, accC[0][2]); accC[1][2] = mfma16(aS1, xb2##Sx, accC[1][2]); \
    accC[0][3] = mfma16(aS0, xb3##Sx, accC[0][3]); accC[1][3] = mfma16(aS1, xb3##Sx, accC[1][3]); \
    s16x8 bsel = (mtp == 0) ? xb0##Sx : (mtp == 1) ? xb1##Sx : (mtp == 2) ? xb2##Sx : xb3##Sx; \
    accS = mfma16(astr, bsel, accS); \
    if (nth == 0){ \
      accB[0] = mfma16(aS0, bone, accB[0]); \
      accB[1] = mfma16(aS1, bone, accB[1]); \
      if (wid == 0) accS8 = mfma16(astr, bone, accS8); \
    } \
  }

  s16x8 xa0A, xa1A, xb0A, xb1A, xb2A, xb3A;
  s16x8 xa0B, xa1B, xb0B, xb1B, xb2B, xb3B;
  f32x4 a0A, a1A, b0A, b1A;
  f32x4 a0B, a1B, b0B, b1B;

  LOADK(0, A);
  #pragma unroll 1
  for (int kst = 0; kst < 64; kst += 2){
    LOADK(kst + 1, B);
    COMP(A);
    if (kst + 2 < 64){ LOADK(kst + 2, A); }
    COMP(B);
  }
#undef COMP
#undef LOADK

  float* Sp = S + (size_t)bh * 19008;   // 132 x 144
  #pragma unroll
  for (int m2 = 0; m2 < 2; ++m2)
    #pragma unroll
    for (int q = 0; q < 4; ++q)
      #pragma unroll
      for (int j = 0; j < 4; ++j)
        atomicAdd(Sp + ((2*mtp + m2)*16 + g*4 + j) * 144 + (4*nth + q)*16 + l15, accC[m2][q][j]);
  if (g == 0){
    #pragma unroll
    for (int j = 0; j < 3; ++j)
      atomicAdd(Sp + (128 + j) * 144 + wid * 16 + l15, accS[j]);
  }
  if (nth == 0 && l15 == 0){
    #pragma unroll
    for (int m2 = 0; m2 < 2; ++m2)
      #pragma unroll
      for (int j = 0; j < 4; ++j)
        atomicAdd(Sp + ((2*mtp + m2)*16 + g*4 + j) * 144 + 128, accB[m2][j]);
  }
  if (wid == 0 && g == 0 && l15 == 0){
    #pragma unroll
    for (int j = 0; j < 3; ++j)
      atomicAdd(Sp + (128 + j) * 144 + 128, accS8[j]);
  }
}

// ---------- kfoldA: G = W~k^T S2 W~v + rank1 + LN gamma/beta corrections -> AM ----------
__global__ __launch_bounds__(256) void kfoldA(
    const float* __restrict__ S, const float* __restrict__ Wk, const float* __restrict__ Wv,
    const float* __restrict__ Wkb, const float* __restrict__ Wvb,
    const float* __restrict__ w1u, const float* __restrict__ scn,
    const float* __restrict__ gk, const float* __restrict__ bbk,
    const float* __restrict__ gv, const float* __restrict__ bbv,
    float* __restrict__ AM)
{
  extern __shared__ float fsm[];
  float* sA = fsm;                 // [128][129]
  float* sS = fsm + 16512;         // [128][33]
  float* svt = fsm + 20736;        // [32]
  float* svb = fsm + 20768;        // [32]
  float* skt = fsm + 20800;        // [128]
  float* skb = fsm + 20928;        // [128]
  const int blk = blockIdx.x, bh = blk >> 2, es = blk & 3;
  const int h = bh & 7;
  const int tid = threadIdx.x;
  const float* Sg = S + (size_t)bh * 19008;
  const float mbk = scn[h], mbv = scn[8 + h];

  for (int idx = tid; idx < 16384; idx += 256){
    int r = idx >> 7, c = idx & 127;
    sA[r * 129 + c] = Sg[r * 144 + c];
  }
  for (int idx = tid; idx < 4096; idx += 256){
    int c = idx >> 5, j = idx & 31;
    sS[c * 33 + j] = Wv[(size_t)c * 1024 + h * 128 + es * 32 + j] - w1u[(8 + h) * 128 + c];
  }
  __syncthreads();
  if (tid < 32){
    float t = 0.f, tb = 0.f;
    for (int c = 0; c < 128; ++c){
      float wv = sS[c * 33 + tid];
      t  += Sg[128 * 144 + c] * wv;
      tb += Sg[130 * 144 + c] * wv;
    }
    svt[tid] = t;
    svb[tid] = tb + Sg[130 * 144 + 128] * (Wvb[h * 128 + es * 32 + tid] - mbv);
  }
  const int r0 = (tid >> 4) * 8, e0 = (tid & 15) * 2;
  float t8[8][2] = {};
  for (int c = 0; c < 128; ++c){
    float w0 = sS[c * 33 + e0], w1_ = sS[c * 33 + e0 + 1];
    #pragma unroll
    for (int i = 0; i < 8; ++i){
      float a = sA[(r0 + i) * 129 + c];
      t8[i][0] += a * w0; t8[i][1] += a * w1_;
    }
  }
  __syncthreads();
  #pragma unroll
  for (int i = 0; i < 8; ++i){
    sS[(r0 + i) * 33 + e0] = t8[i][0];
    sS[(r0 + i) * 33 + e0 + 1] = t8[i][1];
  }
  for (int idx = tid; idx < 16384; idx += 256){
    int c = idx >> 7, n = idx & 127;
    sA[c * 129 + n] = Wk[(size_t)c * 1024 + h * 128 + n] - w1u[h * 128 + c];
  }
  __syncthreads();
  if (tid < 128){
    float t = 0.f, ta = 0.f;
    for (int c = 0; c < 128; ++c){
      float wk = sA[c * 129 + tid];
      t  += Sg[128 * 144 + c] * wk;
      ta += Sg[129 * 144 + c] * wk;
    }
    skt[tid] = t;
    skb[tid] = ta + Sg[129 * 144 + 128] * (Wkb[h * 128 + tid] - mbk);
  }
  float g8[8][2] = {};
  for (int c = 0; c < 128; ++c){
    float t0 = sS[c * 33 + e0], t1 = sS[c * 33 + e0 + 1];
    #pragma unroll
    for (int i = 0; i < 8; ++i){
      float wk = sA[c * 129 + (r0 + i)];
      g8[i][0] += wk * t0; g8[i][1] += wk * t1;
    }
  }
  __syncthreads();
  const float s0 = Sg[128 * 144 + 128];
  #pragma unroll
  for (int i = 0; i < 8; ++i){
    int n = r0 + i;
    float btk = Wkb[h * 128 + n] - mbk;
    #pragma unroll
    for (int jj = 0; jj < 2; ++jj){
      int j = e0 + jj, dv = es * 32 + j;
      float btv = Wvb[h * 128 + dv] - mbv;
      float G = g8[i][jj] + skt[n] * btv + btk * svt[j] + s0 * btk * btv;
      float am = gk[h*128+n] * (gv[h*128+dv] * G + skb[n] * bbv[h*128+dv])
               + bbk[h*128+n] * (gv[h*128+dv] * svb[j] + 32768.f * bbv[h*128+dv]);
      AM[(size_t)bh * 16384 + n * 128 + dv] = am;
    }
  }
}

// ---------- kfoldB: T1 = AM@Wo ; W4F += frag(Wq@T1)/n ; c4 ----------
__global__ __launch_bounds__(256) void kfoldB(
    const float* __restrict__ AM, const float* __restrict__ Wo,
    const float* __restrict__ Wq, const float* __restrict__ Wq_b,
    const float* __restrict__ Wo_b, float* __restrict__ W4F, float* __restrict__ c4)
{
  extern __shared__ float fsm[];
  float* sA = fsm;
  float* sS = fsm + 128 * 129;
  int blk = blockIdx.x;
  int bh = blk >> 2, eq = blk & 3;
  int b = bh >> 3, hs = bh & 7;
  int tid = threadIdx.x;

  for (int idx = tid; idx < 16384; idx += 256){
    int r = idx >> 7, c = idx & 127;
    sA[r * 129 + c] = AM[(size_t)bh * 16384 + idx];
  }
  for (int idx = tid; idx < 4096; idx += 256){
    int r = idx >> 5, c = idx & 31;
    sS[r * 33 + c] = Wo[(size_t)hs * 16384 + r * 128 + eq * 32 + c];
  }
  __syncthreads();

  int r0 = (tid >> 4) * 8, e0 = (tid & 15) * 2;
  float t8[8][2] = {};
  for (int c = 0; c < 128; ++c){
    float wv0 = sS[c * 33 + e0], wv1 = sS[c * 33 + e0 + 1];
    #pragma unroll
    for (int i = 0; i < 8; ++i){
      float a = sA[(r0 + i) * 129 + c];
      t8[i][0] += a * wv0; t8[i][1] += a * wv1;
    }
  }
  __syncthreads();
  #pragma unroll
  for (int i = 0; i < 8; ++i){
    sS[(r0 + i) * 33 + e0]     = t8[i][0];
    sS[(r0 + i) * 33 + e0 + 1] = t8[i][1];
  }
  for (int idx = tid; idx < 16384; idx += 256){
    int r = idx >> 7, c = idx & 127;
    sA[r * 129 + c] = Wq[(size_t)r * 1024 + hs * 128 + c];
  }
  __syncthreads();

  float a8[8][2] = {};
  for (int d = 0; d < 128; ++d){
    float t0 = sS[d * 33 + e0], t1 = sS[d * 33 + e0 + 1];
    #pragma unroll
    for (int i = 0; i < 8; ++i){
      float w = sA[(r0 + i) * 129 + d];
      a8[i][0] += w * t0; a8[i][1] += w * t1;
    }
  }
  const float inv_n = 0.0009765625f;
  #pragma unroll
  for (int i = 0; i < 8; ++i)
    #pragma unroll
    for (int j = 0; j < 2; ++j){
      int cc = r0 + i, nn = eq * 32 + e0 + j;
      int o = ((nn >> 4) * 4 + (cc >> 5)) * 512 + ((cc >> 3) & 3) * 128
            + (nn & 15) * 8 + (cc & 7);
      atomicAdd(W4F + (size_t)b * 16384 + o, a8[i][j] * inv_n);
    }
  if (tid < 32){
    float s = 0.f;
    for (int d = 0; d < 128; ++d) s += Wq_b[hs * 128 + d] * sS[d * 33 + tid];
    if (hs == 0) s += Wo_b[eq * 32 + tid];
    atomicAdd(c4 + b * 128 + eq * 32 + tid, s * inv_n);
  }
}

// ---------- kout = x @ W4[b] + c4[b] ----------
__global__ __launch_bounds__(256, 4) void kout(
    const u16* __restrict__ X, const float* __restrict__ W4F,
    const float* __restrict__ c4, float* __restrict__ out)
{
  __shared__ char sW[32768];
  const int tid = threadIdx.x, wid = tid >> 6, lane = tid & 63, g = lane >> 4, l15 = lane & 15;
  const int blk = blockIdx.x, b = blk >> 8, ch = blk & 255;
  {
    const float* w4b = W4F + (size_t)b * 16384;
    #pragma unroll
    for (int it2 = 0; it2 < 16; ++it2){
      int idx = it2 * 1024 + tid * 4;
      float4 f = *(const float4*)(w4b + idx);
      uint2 w; w.x = cvtpk(f.x, f.y); w.y = cvtpk(f.z, f.w);
      *(uint2*)(sW + idx * 2) = w;
    }
  }
  const char* xr = (const char*)(X + ((size_t)b * 32768 + ch * 128 + wid * 32 + l15) * 128) + g * 16;
  s16x8 af[2][4];
  #pragma unroll
  for (int mt = 0; mt < 2; ++mt)
    #pragma unroll
    for (int ks = 0; ks < 4; ++ks)
      af[mt][ks] = *(const s16x8*)(xr + mt * 4096 + ks * 64);
  __syncthreads();

  f32x4 acc[2][8];
  #pragma unroll
  for (int mt = 0; mt < 2; ++mt)
    #pragma unroll
    for (int nt = 0; nt < 8; ++nt) acc[mt][nt] = f32x4{0.f, 0.f, 0.f, 0.f};

  const u32 wread = (u32)(lane * 16);
  #pragma unroll
  for (int ks = 0; ks < 4; ++ks)
    #pragma unroll
    for (int nt = 0; nt < 8; ++nt){
      s16x8 wf = *(const s16x8*)(sW + wread + (nt * 4 + ks) * 1024);
      acc[0][nt] = mfma16(af[0][ks], wf, acc[0][nt]);
      acc[1][nt] = mfma16(af[1][ks], wf, acc[1][nt]);
    }
  float* ob = out + ((size_t)b * 32768 + ch * 128 + wid * 32) * 128;
  #pragma unroll
  for (int nt = 0; nt < 8; ++nt){
    float c4v = c4[b * 128 + nt * 16 + l15];
    #pragma unroll
    for (int mt = 0; mt < 2; ++mt)
      #pragma unroll
      for (int j = 0; j < 4; ++j)
        ob[(mt * 16 + g * 4 + j) * 128 + nt * 16 + l15] = acc[mt][nt][j] + c4v;
  }
}

extern "C" void kernel_launch(void* const* d_in, const int* in_sizes, int n_in,
                              void* d_out, int out_size, void* d_ws, size_t ws_size,
                              hipStream_t stream){
  const float* v    = (const float*)d_in[0];
  const float* Wq_w = (const float*)d_in[1];
  const float* Wq_b = (const float*)d_in[2];
  const float* Wk_w = (const float*)d_in[3];
  const float* Wk_b = (const float*)d_in[4];
  const float* Wv_w = (const float*)d_in[5];
  const float* Wv_b = (const float*)d_in[6];
  const float* Wo_w = (const float*)d_in[7];
  const float* Wo_b = (const float*)d_in[8];
  const float* lnk_g = (const float*)d_in[9];
  const float* lnk_b = (const float*)d_in[10];
  const float* lnv_g = (const float*)d_in[11];
  const float* lnv_b = (const float*)d_in[12];

  char* ws = (char*)d_ws;
  u16*   X    = (u16*)  (ws);                 // 16,777,216
  u16*   XTF  = (u16*)  (ws + 16777216);      // 16,777,216
  u16*   WF   = (u16*)  (ws + 33554432);      // 524,288
  float* aF   = (float*)(ws + 34078720);      // 2,097,152
  float* bF   = (float*)(ws + 36175872);      // 2,097,152
  float* w1u  = (float*)(ws + 38273024);      // 8,192
  float* scn  = (float*)(ws + 38281216);      // 128 (pad to 38281344)
  float* S    = (float*)(ws + 38281344);      // 1,216,512
  float* W4F  = (float*)(ws + 39497856);      // 131,072
  float* c4   = (float*)(ws + 39628928);      // 1,024
  float* AM   = (float*)(ws + 39630080);      // 1,048,576

  // zero S + W4F + c4 (atomicAdd targets)
  hipMemsetAsync(ws + 38281344, 0, 1348608, stream);

  hipLaunchKernelGGL(kprep, dim3(528), dim3(256), 0, stream,
                     v, Wk_w, Wv_w, Wk_b, Wv_b, X, XTF, WF, w1u, scn);

  hipLaunchKernelGGL(kstat, dim3(512), dim3(512), 0, stream,
                     X, WF, Wk_b, Wv_b, aF, bF);

  hipLaunchKernelGGL(kS2, dim3(256), dim3(512), 0, stream, XTF, aF, bF, S);

  (void)hipFuncSetAttribute((const void*)kfoldA,
                            hipFuncAttributeMaxDynamicSharedMemorySize, 84224);
  hipLaunchKernelGGL(kfoldA, dim3(64), dim3(256), 84224, stream,
                     S, Wk_w, Wv_w, Wk_b, Wv_b, w1u, scn,
                     lnk_g, lnk_b, lnv_g, lnv_b, AM);

  (void)hipFuncSetAttribute((const void*)kfoldB,
                            hipFuncAttributeMaxDynamicSharedMemorySize, 82944);
  hipLaunchKernelGGL(kfoldB, dim3(64), dim3(256), 82944, stream,
                     AM, Wo_w, Wq_w, Wq_b, Wo_b, W4F, c4);

  hipLaunchKernelGGL(kout, dim3(512), dim3(256), 0, stream, X, W4F, c4, (float*)d_out);
}